// Round 16
// baseline (244.757 us; speedup 1.0000x reference)
//
#include <hip/hip_runtime.h>

// out = B @ (X @ W) = (B @ X) @ W  — fused, NO intermediate xp:
//   wtrans: Wt_bf16[n][k] = bf16(W[k][n])
//   hist/scan/fill: CSR build (by output row)
//   fused:  16-wave blocks; per iter, wave w gathers out-row it*16+w from raw
//           fp32 X (batched independent 1KB reads, fp32 accum), deposits bf16
//           into a double-buffered 16-row LDS tile (XOR-swizzled); each wave
//           projects the tile against its 16-col W-slice held in 32 VGPRs
//           (8 MFMA/iter); 64B-aligned fp32 stores. One barrier per iter;
//           next iter's gather batch is issued BEFORE this iter's MFMAs.

typedef short bf16x8 __attribute__((ext_vector_type(8)));
typedef float f32x4  __attribute__((ext_vector_type(4)));

#define FGRID 256

static __device__ __forceinline__ unsigned short f2bf(float f) {
    union { float f; unsigned u; } a; a.f = f;
    unsigned r = a.u + 0x7FFFu + ((a.u >> 16) & 1u);   // RNE
    return (unsigned short)(r >> 16);
}

__global__ __launch_bounds__(256) void wtrans_kernel(
    const float* __restrict__ W, unsigned short* __restrict__ Wt)
{
    int k = blockIdx.x;
    int n = threadIdx.x;
    Wt[(size_t)n * 256 + k] = f2bf(W[(size_t)k * 256 + n]);
}

__global__ __launch_bounds__(256) void hist_kernel(
    const int* __restrict__ b_rows, int* __restrict__ cnt, int nnz)
{
    int i = blockIdx.x * 256 + threadIdx.x;
    if (i < nnz) atomicAdd(&cnt[b_rows[i]], 1);
}

__global__ __launch_bounds__(1024) void scan_part_kernel(
    const int* __restrict__ cnt, int* __restrict__ partials, int M)
{
    int tid = threadIdx.x;
    int base = blockIdx.x * 4096;
    int s = 0;
    #pragma unroll
    for (int k = 0; k < 4; ++k) {
        int i = base + k * 1024 + tid;
        if (i < M) s += cnt[i];
    }
    #pragma unroll
    for (int d = 1; d < 64; d <<= 1) s += __shfl_xor(s, d);
    __shared__ int wsum[16];
    int lane = tid & 63, wid = tid >> 6;
    if (lane == 0) wsum[wid] = s;
    __syncthreads();
    if (tid == 0) {
        int t = 0;
        #pragma unroll
        for (int w = 0; w < 16; ++w) t += wsum[w];
        partials[blockIdx.x] = t;
    }
}

__global__ __launch_bounds__(64) void scan_mid_kernel(
    int* __restrict__ partials, int* __restrict__ off, int np, int M)
{
    int lane = threadIdx.x;
    int v = (lane < np) ? partials[lane] : 0;
    int x = v;
    #pragma unroll
    for (int d = 1; d < 64; d <<= 1) { int y = __shfl_up(x, d); if (lane >= d) x += y; }
    if (lane < np) partials[lane] = x - v;
    if (lane == 63) off[M] = x;
}

__global__ __launch_bounds__(1024) void scan_apply_kernel(
    const int* __restrict__ cnt, const int* __restrict__ partials,
    int* __restrict__ off, int* __restrict__ cursor, int M)
{
    int tid = threadIdx.x;
    int base = blockIdx.x * 4096 + tid * 4;
    int4 v = make_int4(0, 0, 0, 0);
    if (base + 3 < M) v = *reinterpret_cast<const int4*>(cnt + base);
    else {
        if (base + 0 < M) v.x = cnt[base + 0];
        if (base + 1 < M) v.y = cnt[base + 1];
        if (base + 2 < M) v.z = cnt[base + 2];
    }
    int s1 = v.x + v.y, s2 = s1 + v.z, tsum = s2 + v.w;
    int x = tsum;
    int lane = tid & 63, wid = tid >> 6;
    #pragma unroll
    for (int d = 1; d < 64; d <<= 1) { int y = __shfl_up(x, d); if (lane >= d) x += y; }
    __shared__ int wsum[16];
    if (lane == 63) wsum[wid] = x;
    __syncthreads();
    if (wid == 0 && lane < 16) {
        int w = wsum[lane];
        int xx = w;
        #pragma unroll
        for (int d = 1; d < 16; d <<= 1) { int y = __shfl_up(xx, d); if (lane >= d) xx += y; }
        wsum[lane] = xx - w;
    }
    __syncthreads();
    int excl = (x - tsum) + wsum[wid] + partials[blockIdx.x];
    int o0 = excl, o1 = excl + v.x, o2 = excl + s1, o3 = excl + s2;
    if (base + 0 < M) { off[base + 0] = o0; cursor[base + 0] = o0; }
    if (base + 1 < M) { off[base + 1] = o1; cursor[base + 1] = o1; }
    if (base + 2 < M) { off[base + 2] = o2; cursor[base + 2] = o2; }
    if (base + 3 < M) { off[base + 3] = o3; cursor[base + 3] = o3; }
}

__global__ __launch_bounds__(256) void fill_kernel(
    const float* __restrict__ b_vals, const int* __restrict__ b_rows,
    const int* __restrict__ b_cols, int* __restrict__ cursor,
    int* __restrict__ csr_col, float* __restrict__ csr_val, int nnz)
{
    int i = blockIdx.x * 256 + threadIdx.x;
    if (i < nnz) {
        int r = b_rows[i];
        int pos = atomicAdd(&cursor[r], 1);
        csr_col[pos] = b_cols[i];
        csr_val[pos] = b_vals[i];
    }
}

// Gather one out-row's first edge batch: issue loads only (caller reduces).
#define GATHER_LOAD(row)                                                      \
    gs = off[row]; ge = off[row + 1];                                         \
    gn = ge - gs; if (gn > 8) gn = 8;                                         \
    _Pragma("unroll")                                                         \
    for (int t = 0; t < 8; ++t)                                               \
        if (t < gn) { gc[t] = csr_col[gs + t]; gv[t] = csr_val[gs + t]; }     \
    _Pragma("unroll")                                                         \
    for (int t = 0; t < 8; ++t)                                               \
        if (t < gn) gx[t] = x4[(size_t)gc[t] * 64 + lane];

__global__ __launch_bounds__(1024, 4) void fused_kernel(
    const float* __restrict__ X, const unsigned short* __restrict__ Wt,
    const float* __restrict__ csr_val, const int* __restrict__ csr_col,
    const int* __restrict__ off, float* __restrict__ out, int ntiles)
{
    __shared__ __align__(16) unsigned char tile[2][16 * 512];   // 16 KB

    int tid = threadIdx.x;
    int lane = tid & 63, w = tid >> 6;       // w: row-in-tile AND 16-col slice
    int arow = lane & 15, kg = lane >> 4;
    int xo_w = (w & 7) << 4;
    int xo_a = (arow & 7) << 4;

    // B-slice (cols [w*16, +16)) in registers: 8 frags = 32 VGPR (r11-proven)
    bf16x8 breg[8];
    {
        const char* wt = reinterpret_cast<const char*>(Wt);
        size_t nb = (size_t)(w * 16 + arow) * 512 + kg * 16;
        #pragma unroll
        for (int s = 0; s < 8; ++s)
            breg[s] = *reinterpret_cast<const bf16x8*>(wt + nb + s * 64);
    }

    const float4* x4 = reinterpret_cast<const float4*>(X);

    int gs, ge, gn;
    int gc[8]; float gv[8]; float4 gx[8];

    // ---- prologue: gather + deposit tile 0 (iter r = 0)
    {
        int row = blockIdx.x * 16 + w;
        float4 acc = make_float4(0.f, 0.f, 0.f, 0.f);
        GATHER_LOAD(row);
        for (;;) {
            #pragma unroll
            for (int t = 0; t < 8; ++t)
                if (t < gn) {
                    acc.x += gv[t] * gx[t].x; acc.y += gv[t] * gx[t].y;
                    acc.z += gv[t] * gx[t].z; acc.w += gv[t] * gx[t].w;
                }
            gs += gn;
            if (gs >= ge) break;
            gn = ge - gs; if (gn > 8) gn = 8;
            #pragma unroll
            for (int t = 0; t < 8; ++t)
                if (t < gn) { gc[t] = csr_col[gs + t]; gv[t] = csr_val[gs + t]; }
            #pragma unroll
            for (int t = 0; t < 8; ++t)
                if (t < gn) gx[t] = x4[(size_t)gc[t] * 64 + lane];
        }
        ushort4 h;
        h.x = f2bf(acc.x); h.y = f2bf(acc.y); h.z = f2bf(acc.z); h.w = f2bf(acc.w);
        *reinterpret_cast<ushort4*>(tile[0] + w * 512 + ((lane * 8) ^ xo_w)) = h;
    }
    __syncthreads();

    for (int r = 0;; ++r) {
        int it  = blockIdx.x + r * FGRID;        // current tile (valid)
        int itn = it + FGRID;                    // next tile
        bool hasn = (itn < ntiles);
        int p = r & 1;

        // issue next row's first gather batch BEFORE compute (latency hides)
        if (hasn) { int row = itn * 16 + w; GATHER_LOAD(row); }

        // ---- compute current tile: A from LDS, B from registers
        f32x4 macc = {};
        #pragma unroll
        for (int s = 0; s < 8; ++s) {
            bf16x8 a = *reinterpret_cast<const bf16x8*>(
                tile[p] + arow * 512 + ((s * 64 + kg * 16) ^ xo_a));
            macc = __builtin_amdgcn_mfma_f32_16x16x32_bf16(a, breg[s], macc, 0, 0, 0);
        }
        // store: rows R+kg*4+rr, col w*16+arow (16 cols x 4B = 64B lines)
        int R = it * 16;
        #pragma unroll
        for (int rr = 0; rr < 4; ++rr)
            out[(size_t)(R + kg * 4 + rr) * 256 + w * 16 + arow] = macc[rr];

        if (!hasn) break;

        // ---- reduce gather, handle rare extra batches, deposit into tile[p^1]
        float4 acc = make_float4(0.f, 0.f, 0.f, 0.f);
        for (;;) {
            #pragma unroll
            for (int t = 0; t < 8; ++t)
                if (t < gn) {
                    acc.x += gv[t] * gx[t].x; acc.y += gv[t] * gx[t].y;
                    acc.z += gv[t] * gx[t].z; acc.w += gv[t] * gx[t].w;
                }
            gs += gn;
            if (gs >= ge) break;
            gn = ge - gs; if (gn > 8) gn = 8;
            #pragma unroll
            for (int t = 0; t < 8; ++t)
                if (t < gn) { gc[t] = csr_col[gs + t]; gv[t] = csr_val[gs + t]; }
            #pragma unroll
            for (int t = 0; t < 8; ++t)
                if (t < gn) gx[t] = x4[(size_t)gc[t] * 64 + lane];
        }
        ushort4 h;
        h.x = f2bf(acc.x); h.y = f2bf(acc.y); h.z = f2bf(acc.z); h.w = f2bf(acc.w);
        *reinterpret_cast<ushort4*>(tile[p ^ 1] + w * 512 + ((lane * 8) ^ xo_w)) = h;
        __syncthreads();
    }
}

extern "C" void kernel_launch(void* const* d_in, const int* in_sizes, int n_in,
                              void* d_out, int out_size, void* d_ws, size_t ws_size,
                              hipStream_t stream) {
    const float* x_src  = (const float*)d_in[0];
    const float* W      = (const float*)d_in[1];
    const float* b_vals = (const float*)d_in[2];
    const int*   b_rows = (const int*)d_in[3];
    const int*   b_cols = (const int*)d_in[4];

    const int C = 256;
    const int M = out_size / C;
    const int nnz = in_sizes[2];

    char* ws = (char*)d_ws;
    unsigned short* Wt = (unsigned short*)ws;           ws += 256 * 256 * 2;
    int*   cnt     = (int*)ws;                          ws += (size_t)M * 4;
    int*   off     = (int*)ws;                          ws += (size_t)(M + 1) * 4;
    int*   cursor  = (int*)ws;                          ws += (size_t)M * 4;
    int*   partials= (int*)ws;                          ws += 64 * 4;
    int*   csr_col = (int*)ws;                          ws += (size_t)nnz * 4;
    float* csr_val = (float*)ws;                        ws += (size_t)nnz * 4;

    float* out = (float*)d_out;

    hipMemsetAsync(cnt, 0, (size_t)M * 4, stream);

    wtrans_kernel<<<256, 256, 0, stream>>>(W, Wt);

    int nblk_nnz = (nnz + 255) / 256;
    hist_kernel<<<nblk_nnz, 256, 0, stream>>>(b_rows, cnt, nnz);

    int nb = (M + 4095) / 4096;
    scan_part_kernel<<<nb, 1024, 0, stream>>>(cnt, partials, M);
    scan_mid_kernel<<<1, 64, 0, stream>>>(partials, off, nb, M);
    scan_apply_kernel<<<nb, 1024, 0, stream>>>(cnt, partials, off, cursor, M);

    fill_kernel<<<nblk_nnz, 256, 0, stream>>>(b_vals, b_rows, b_cols, cursor,
                                              csr_col, csr_val, nnz);

    int ntiles = M / 16;                       // M=100000 -> 6250 (M%16==0)
    fused_kernel<<<FGRID, 1024, 0, stream>>>(x_src, Wt, csr_val, csr_col, off,
                                             out, ntiles);
}

// Round 17
// 199.689 us; speedup vs baseline: 1.2257x; 1.2257x over previous
//
#include <hip/hip_runtime.h>

// out = B @ (X @ W)  (r10 structure; gather reworked for 2 rows/wave MLP):
//   wtrans: Wt_bf16[n][k] = bf16(W[k][n])
//   hist/scan/fill: CSR build
//   proj2:  x_proj_bf16 = bf16(X @ W), W entirely in LDS, 16 waves/block
//   gather2: TWO out rows per wave; both rows' 8-deep csr+gather batches
//            issued back-to-back (~16 loads in flight); fp32 accum; direct
//            unpermuting stores. Tail batches (deg>8, ~2%) per-row loops.

typedef short bf16x8 __attribute__((ext_vector_type(8)));
typedef float f32x4  __attribute__((ext_vector_type(4)));

static __device__ __forceinline__ unsigned short f2bf(float f) {
    union { float f; unsigned u; } a; a.f = f;
    unsigned r = a.u + 0x7FFFu + ((a.u >> 16) & 1u);   // RNE
    return (unsigned short)(r >> 16);
}

static __device__ __forceinline__ float bf2f(unsigned short h) {
    union { unsigned u; float f; } a; a.u = (unsigned)h << 16;
    return a.f;
}

static __device__ __forceinline__ unsigned pack2(float f0, float f1) {
    return (unsigned)f2bf(f0) | ((unsigned)f2bf(f1) << 16);
}

static __device__ __forceinline__ bf16x8 cvt8(float4 lo, float4 hi) {
    union { bf16x8 v; unsigned u[4]; } r;
    r.u[0] = pack2(lo.x, lo.y);
    r.u[1] = pack2(lo.z, lo.w);
    r.u[2] = pack2(hi.x, hi.y);
    r.u[3] = pack2(hi.z, hi.w);
    return r.v;
}

__global__ __launch_bounds__(256) void wtrans_kernel(
    const float* __restrict__ W, unsigned short* __restrict__ Wt)
{
    int k = blockIdx.x;
    int n = threadIdx.x;
    Wt[(size_t)n * 256 + k] = f2bf(W[(size_t)k * 256 + n]);
}

__global__ __launch_bounds__(256) void hist_kernel(
    const int* __restrict__ b_rows, int* __restrict__ cnt, int nnz)
{
    int i = blockIdx.x * 256 + threadIdx.x;
    if (i < nnz) atomicAdd(&cnt[b_rows[i]], 1);
}

__global__ __launch_bounds__(1024) void scan_part_kernel(
    const int* __restrict__ cnt, int* __restrict__ partials, int M)
{
    int tid = threadIdx.x;
    int base = blockIdx.x * 4096;
    int s = 0;
    #pragma unroll
    for (int k = 0; k < 4; ++k) {
        int i = base + k * 1024 + tid;
        if (i < M) s += cnt[i];
    }
    #pragma unroll
    for (int d = 1; d < 64; d <<= 1) s += __shfl_xor(s, d);
    __shared__ int wsum[16];
    int lane = tid & 63, wid = tid >> 6;
    if (lane == 0) wsum[wid] = s;
    __syncthreads();
    if (tid == 0) {
        int t = 0;
        #pragma unroll
        for (int w = 0; w < 16; ++w) t += wsum[w];
        partials[blockIdx.x] = t;
    }
}

__global__ __launch_bounds__(64) void scan_mid_kernel(
    int* __restrict__ partials, int* __restrict__ off, int np, int M)
{
    int lane = threadIdx.x;
    int v = (lane < np) ? partials[lane] : 0;
    int x = v;
    #pragma unroll
    for (int d = 1; d < 64; d <<= 1) { int y = __shfl_up(x, d); if (lane >= d) x += y; }
    if (lane < np) partials[lane] = x - v;
    if (lane == 63) off[M] = x;
}

__global__ __launch_bounds__(1024) void scan_apply_kernel(
    const int* __restrict__ cnt, const int* __restrict__ partials,
    int* __restrict__ off, int* __restrict__ cursor, int M)
{
    int tid = threadIdx.x;
    int base = blockIdx.x * 4096 + tid * 4;
    int4 v = make_int4(0, 0, 0, 0);
    if (base + 3 < M) v = *reinterpret_cast<const int4*>(cnt + base);
    else {
        if (base + 0 < M) v.x = cnt[base + 0];
        if (base + 1 < M) v.y = cnt[base + 1];
        if (base + 2 < M) v.z = cnt[base + 2];
    }
    int s1 = v.x + v.y, s2 = s1 + v.z, tsum = s2 + v.w;
    int x = tsum;
    int lane = tid & 63, wid = tid >> 6;
    #pragma unroll
    for (int d = 1; d < 64; d <<= 1) { int y = __shfl_up(x, d); if (lane >= d) x += y; }
    __shared__ int wsum[16];
    if (lane == 63) wsum[wid] = x;
    __syncthreads();
    if (wid == 0 && lane < 16) {
        int w = wsum[lane];
        int xx = w;
        #pragma unroll
        for (int d = 1; d < 16; d <<= 1) { int y = __shfl_up(xx, d); if (lane >= d) xx += y; }
        wsum[lane] = xx - w;
    }
    __syncthreads();
    int excl = (x - tsum) + wsum[wid] + partials[blockIdx.x];
    int o0 = excl, o1 = excl + v.x, o2 = excl + s1, o3 = excl + s2;
    if (base + 0 < M) { off[base + 0] = o0; cursor[base + 0] = o0; }
    if (base + 1 < M) { off[base + 1] = o1; cursor[base + 1] = o1; }
    if (base + 2 < M) { off[base + 2] = o2; cursor[base + 2] = o2; }
    if (base + 3 < M) { off[base + 3] = o3; cursor[base + 3] = o3; }
}

__global__ __launch_bounds__(256) void fill_kernel(
    const float* __restrict__ b_vals, const int* __restrict__ b_rows,
    const int* __restrict__ b_cols, int* __restrict__ cursor,
    int* __restrict__ csr_col, float* __restrict__ csr_val, int nnz)
{
    int i = blockIdx.x * 256 + threadIdx.x;
    if (i < nnz) {
        int r = b_rows[i];
        int pos = atomicAdd(&cursor[r], 1);
        csr_col[pos] = b_cols[i];
        csr_val[pos] = b_vals[i];
    }
}

// x_proj = bf16(X @ W) with W entirely in LDS; 16 waves/block (4/SIMD).
// LDS byte(n, koff) = n*512 + (koff ^ ((n&7)<<4)), koff = k*2.
// xp contract: row halfword [g*64+a*4+t] = true channel {64g+a+16t}.
__global__ __launch_bounds__(1024, 4) void proj2_kernel(
    const float* __restrict__ X, const unsigned short* __restrict__ Wt,
    unsigned short* __restrict__ xp, int ntiles, int tpw)
{
    __shared__ __align__(16) unsigned char wlds[256 * 512];   // 128 KB

    int tid = threadIdx.x;
    int lane = tid & 63, wid = tid >> 6;

    const char* wtg = reinterpret_cast<const char*>(Wt);
    #pragma unroll
    for (int itc = 0; itc < 8; ++itc) {
        int c = tid + itc * 1024;              // chunk 0..8191
        int n = c >> 5, j = c & 31;
        uint4 w16 = *reinterpret_cast<const uint4*>(wtg + (size_t)n * 512 + j * 16);
        int b = n * 512 + ((j * 16) ^ ((n & 7) << 4));
        *reinterpret_cast<uint4*>(wlds + b) = w16;
    }
    __syncthreads();

    int arow = lane & 15;
    int kg = lane >> 4;                        // 0..3
    int xo = (arow & 7) << 4;                  // read-side swizzle

    for (int it = 0; it < tpw; ++it) {
        int tile = blockIdx.x * (tpw << 4) + (it << 4) + wid;
        if (tile >= ntiles) break;
        int R = tile * 16;

        const float* ap = X + (size_t)(R + arow) * 256 + kg * 8;

        f32x4 acc[16] = {};
        #pragma unroll
        for (int half = 0; half < 2; ++half) {
            float4 buf[8];
            #pragma unroll
            for (int s = 0; s < 4; ++s) {
                int ss = half * 4 + s;
                buf[2 * s]     = *reinterpret_cast<const float4*>(ap + ss * 32);
                buf[2 * s + 1] = *reinterpret_cast<const float4*>(ap + ss * 32 + 4);
            }
            #pragma unroll
            for (int s = 0; s < 4; ++s) {
                int ss = half * 4 + s;
                bf16x8 a = cvt8(buf[2 * s], buf[2 * s + 1]);
                int koff = (ss * 64 + kg * 16) ^ xo;
                #pragma unroll
                for (int nt = 0; nt < 16; ++nt) {
                    int n = nt * 16 + arow;
                    bf16x8 b = *reinterpret_cast<const bf16x8*>(wlds + n * 512 + koff);
                    acc[nt] = __builtin_amdgcn_mfma_f32_16x16x32_bf16(a, b, acc[nt], 0, 0, 0);
                }
            }
        }

        #pragma unroll
        for (int rr = 0; rr < 4; ++rr) {
            int row = R + kg * 4 + rr;
            #pragma unroll
            for (int g = 0; g < 4; ++g) {
                ushort4 h;
                h.x = f2bf(acc[4 * g + 0][rr]);
                h.y = f2bf(acc[4 * g + 1][rr]);
                h.z = f2bf(acc[4 * g + 2][rr]);
                h.w = f2bf(acc[4 * g + 3][rr]);
                *reinterpret_cast<ushort4*>(xp + (size_t)row * 256 + g * 64 + arow * 4) = h;
            }
        }
    }
}

// TWO out rows per wave. Both rows' first 8-deep batches issued back-to-back
// (~16 independent loads in flight); fp32 accum; tails per-row (deg>8, rare).
// Requires M % 8 == 0 (M=100000 ok). xp unpermute as in r10.
__global__ __launch_bounds__(256) void gather2_kernel(
    const unsigned short* __restrict__ xp, const float* __restrict__ csr_val,
    const int* __restrict__ csr_col, const int* __restrict__ off,
    float* __restrict__ out, int M)
{
    int wid = threadIdx.x >> 6, lane = threadIdx.x & 63;
    int row0 = blockIdx.x * 8 + wid * 2;     // row1 = row0 + 1
    if (row0 >= M) return;

    int s0 = off[row0], e0 = off[row0 + 1], e1 = off[row0 + 2];

    float a00 = 0.f, a01 = 0.f, a02 = 0.f, a03 = 0.f;
    float a10 = 0.f, a11 = 0.f, a12 = 0.f, a13 = 0.f;

    // first batches for both rows, issued together
    int n0 = e0 - s0; if (n0 > 8) n0 = 8;
    int n1 = e1 - e0; if (n1 > 8) n1 = 8;
    int c0[8], c1[8]; float v0[8], v1[8]; ushort4 x0[8], x1[8];
    #pragma unroll
    for (int t = 0; t < 8; ++t)
        if (t < n0) { c0[t] = csr_col[s0 + t]; v0[t] = csr_val[s0 + t]; }
    #pragma unroll
    for (int t = 0; t < 8; ++t)
        if (t < n1) { c1[t] = csr_col[e0 + t]; v1[t] = csr_val[e0 + t]; }
    #pragma unroll
    for (int t = 0; t < 8; ++t)
        if (t < n0) x0[t] = *reinterpret_cast<const ushort4*>(
            xp + (size_t)c0[t] * 256 + lane * 4);
    #pragma unroll
    for (int t = 0; t < 8; ++t)
        if (t < n1) x1[t] = *reinterpret_cast<const ushort4*>(
            xp + (size_t)c1[t] * 256 + lane * 4);
    #pragma unroll
    for (int t = 0; t < 8; ++t)
        if (t < n0) {
            a00 += v0[t] * bf2f(x0[t].x); a01 += v0[t] * bf2f(x0[t].y);
            a02 += v0[t] * bf2f(x0[t].z); a03 += v0[t] * bf2f(x0[t].w);
        }
    #pragma unroll
    for (int t = 0; t < 8; ++t)
        if (t < n1) {
            a10 += v1[t] * bf2f(x1[t].x); a11 += v1[t] * bf2f(x1[t].y);
            a12 += v1[t] * bf2f(x1[t].z); a13 += v1[t] * bf2f(x1[t].w);
        }

    // rare tails (deg > 8): per-row 8-deep loops
    for (int j = s0 + n0; j < e0; j += 8) {
        int nb = e0 - j; if (nb > 8) nb = 8;
        #pragma unroll
        for (int t = 0; t < 8; ++t)
            if (t < nb) { c0[t] = csr_col[j + t]; v0[t] = csr_val[j + t]; }
        #pragma unroll
        for (int t = 0; t < 8; ++t)
            if (t < nb) x0[t] = *reinterpret_cast<const ushort4*>(
                xp + (size_t)c0[t] * 256 + lane * 4);
        #pragma unroll
        for (int t = 0; t < 8; ++t)
            if (t < nb) {
                a00 += v0[t] * bf2f(x0[t].x); a01 += v0[t] * bf2f(x0[t].y);
                a02 += v0[t] * bf2f(x0[t].z); a03 += v0[t] * bf2f(x0[t].w);
            }
    }
    for (int j = e0 + n1; j < e1; j += 8) {
        int nb = e1 - j; if (nb > 8) nb = 8;
        #pragma unroll
        for (int t = 0; t < 8; ++t)
            if (t < nb) { c1[t] = csr_col[j + t]; v1[t] = csr_val[j + t]; }
        #pragma unroll
        for (int t = 0; t < 8; ++t)
            if (t < nb) x1[t] = *reinterpret_cast<const ushort4*>(
                xp + (size_t)c1[t] * 256 + lane * 4);
        #pragma unroll
        for (int t = 0; t < 8; ++t)
            if (t < nb) {
                a10 += v1[t] * bf2f(x1[t].x); a11 += v1[t] * bf2f(x1[t].y);
                a12 += v1[t] * bf2f(x1[t].z); a13 += v1[t] * bf2f(x1[t].w);
            }
    }

    // lane holds true channels {64*(lane>>4) + (lane&15) + 16*t}
    int col0 = (lane >> 4) * 64 + (lane & 15);
    float* o0 = out + (size_t)row0 * 256;
    float* o1 = o0 + 256;
    o0[col0 +  0] = a00; o0[col0 + 16] = a01;
    o0[col0 + 32] = a02; o0[col0 + 48] = a03;
    o1[col0 +  0] = a10; o1[col0 + 16] = a11;
    o1[col0 + 32] = a12; o1[col0 + 48] = a13;
}

extern "C" void kernel_launch(void* const* d_in, const int* in_sizes, int n_in,
                              void* d_out, int out_size, void* d_ws, size_t ws_size,
                              hipStream_t stream) {
    const float* x_src  = (const float*)d_in[0];
    const float* W      = (const float*)d_in[1];
    const float* b_vals = (const float*)d_in[2];
    const int*   b_rows = (const int*)d_in[3];
    const int*   b_cols = (const int*)d_in[4];

    const int C = 256;
    const int M = out_size / C;
    const int nnz = in_sizes[2];
    const int N = in_sizes[0] / C;

    char* ws = (char*)d_ws;
    unsigned short* Wt = (unsigned short*)ws;           ws += 256 * 256 * 2;
    int*   cnt     = (int*)ws;                          ws += (size_t)M * 4;
    int*   off     = (int*)ws;                          ws += (size_t)(M + 1) * 4;
    int*   cursor  = (int*)ws;                          ws += (size_t)M * 4;
    int*   partials= (int*)ws;                          ws += 64 * 4;
    int*   csr_col = (int*)ws;                          ws += (size_t)nnz * 4;
    float* csr_val = (float*)ws;                        ws += (size_t)nnz * 4;
    ws = (char*)(((size_t)ws + 63) & ~(size_t)63);
    unsigned short* xp = (unsigned short*)ws;           // N*512 bytes (~102 MB)

    float* out = (float*)d_out;

    hipMemsetAsync(cnt, 0, (size_t)M * 4, stream);

    wtrans_kernel<<<256, 256, 0, stream>>>(W, Wt);

    int nblk_nnz = (nnz + 255) / 256;
    hist_kernel<<<nblk_nnz, 256, 0, stream>>>(b_rows, cnt, nnz);

    int nb = (M + 4095) / 4096;
    scan_part_kernel<<<nb, 1024, 0, stream>>>(cnt, partials, M);
    scan_mid_kernel<<<1, 64, 0, stream>>>(partials, off, nb, M);
    scan_apply_kernel<<<nb, 1024, 0, stream>>>(cnt, partials, off, cursor, M);

    fill_kernel<<<nblk_nnz, 256, 0, stream>>>(b_vals, b_rows, b_cols, cursor,
                                              csr_col, csr_val, nnz);

    int ntiles = N / 16;                       // N=200000 -> 12500
    int grid_p = 256;
    int tpw = (ntiles + grid_p * 16 - 1) / (grid_p * 16);   // 4
    proj2_kernel<<<grid_p, 1024, 0, stream>>>(x_src, Wt, xp, ntiles, tpw);

    gather2_kernel<<<(M + 7) / 8, 256, 0, stream>>>(xp, csr_val, csr_col, off, out, M);
}